// Round 1
// baseline (787.176 us; speedup 1.0000x reference)
//
#include <hip/hip_runtime.h>
#include <math.h>

// CPC loss, MI355X. B=16 T=512 D=256, horizons {1,5,21}, 128 negatives, temp 0.07.
// ws layout: [0, 8192*256) all_z (normalized z rows, fp32)
//            [8192*256, 2*8192*256) z_pred scratch (raw, per-horizon, reused)
constexpr int Bc = 16, Tc = 512, Dc = 256, NNEGc = 128, BTc = Bc * Tc;
constexpr float TEMP_INV = 1.0f / 0.07f;

__global__ void k_zero(float* out) { out[0] = 0.0f; }

// One wave per row: normalize 256-float row.
__global__ __launch_bounds__(256) void k_norm(const float* __restrict__ z,
                                              float* __restrict__ az) {
    int wid = threadIdx.x >> 6, lane = threadIdx.x & 63;
    int row = (blockIdx.x << 2) + wid;  // grid = BT/4, always in range
    float4 v = reinterpret_cast<const float4*>(z)[row * 64 + lane];
    float s = v.x * v.x + v.y * v.y + v.z * v.z + v.w * v.w;
#pragma unroll
    for (int off = 32; off; off >>= 1) s += __shfl_xor(s, off, 64);
    float inv = 1.0f / fmaxf(sqrtf(s), 1e-12f);
    float4 o = make_float4(v.x * inv, v.y * inv, v.z * inv, v.w * inv);
    reinterpret_cast<float4*>(az)[row * 64 + lane] = o;
}

// z_pred[n][e] = sum_d z_seq[src(n)][d] * W[e*256+d], raw (unnormalized).
// Block: 32 rows x 256 cols, 256 threads (thread t = col t, 32 row-accs).
// A tile (32x256) in LDS, broadcast-read; W row streamed via L1.
__global__ __launch_bounds__(256) void k_pred(const float* __restrict__ z,
                                              const float* __restrict__ W,
                                              float* __restrict__ zp,
                                              int L, int N) {
    __shared__ float As[32 * Dc];  // 32 KB
    int n0 = blockIdx.x * 32;
    int t = threadIdx.x;
#pragma unroll
    for (int p = 0; p < 8; ++p) {
        int f = t + p * 256;       // float4 index within tile (2048 total)
        int r = f >> 6, c4 = f & 63;
        int n = n0 + r; if (n >= N) n = N - 1;
        int b = n / L, l = n - b * L;
        float4 v = reinterpret_cast<const float4*>(z)[(b * Tc + l) * 64 + c4];
        reinterpret_cast<float4*>(As)[r * 64 + c4] = v;
    }
    __syncthreads();
    float acc[32];
#pragma unroll
    for (int r = 0; r < 32; ++r) acc[r] = 0.0f;
    const float4* Wrow = reinterpret_cast<const float4*>(W) + t * 64;
    const float4* As4 = reinterpret_cast<const float4*>(As);
    for (int k4 = 0; k4 < 64; ++k4) {
        float4 w = Wrow[k4];
#pragma unroll
        for (int r = 0; r < 32; ++r) {
            float4 a = As4[r * 64 + k4];  // wave-broadcast
            acc[r] += a.x * w.x + a.y * w.y + a.z * w.z + a.w * w.w;
        }
    }
#pragma unroll
    for (int r = 0; r < 32; ++r) {
        int n = n0 + r;
        if (n < N) zp[n * Dc + t] = acc[r];
    }
}

// One wave per row n: normalize z_pred row (into LDS), pos dot,
// 2 negatives/lane gather-dots, wave logsumexp, atomicAdd weighted loss.
__global__ __launch_bounds__(256) void k_loss(const float* __restrict__ az,
                                              const float* __restrict__ zp,
                                              const int* __restrict__ nidx,
                                              float* __restrict__ out,
                                              int L, int N, int kh, float scale) {
    __shared__ float zps[4][Dc];
    int wid = threadIdx.x >> 6, lane = threadIdx.x & 63;
    int n = (blockIdx.x << 2) + wid;
    if (n >= N) return;  // wave-uniform exit

    // normalize z_pred row into LDS
    float4 v = reinterpret_cast<const float4*>(zp)[n * 64 + lane];
    float s = v.x * v.x + v.y * v.y + v.z * v.z + v.w * v.w;
#pragma unroll
    for (int off = 32; off; off >>= 1) s += __shfl_xor(s, off, 64);
    float inv = 1.0f / fmaxf(sqrtf(s), 1e-12f);
    v.x *= inv; v.y *= inv; v.z *= inv; v.w *= inv;
    reinterpret_cast<float4*>(zps[wid])[lane] = v;

    // positive logit: dot with all_z[b*T + l + k]
    int b = n / L, l = n - b * L;
    float4 p = reinterpret_cast<const float4*>(az)[(b * Tc + l + kh) * 64 + lane];
    float pd = v.x * p.x + v.y * p.y + v.z * p.z + v.w * p.w;
#pragma unroll
    for (int off = 32; off; off >>= 1) pd += __shfl_xor(pd, off, 64);
    float pos = pd * TEMP_INV;

    // negatives: lane handles j=lane and j=lane+64
    int i1 = nidx[n * NNEGc + lane];
    int i2 = nidx[n * NNEGc + lane + 64];
    const float4* r1 = reinterpret_cast<const float4*>(az) + i1 * 64;
    const float4* r2 = reinterpret_cast<const float4*>(az) + i2 * 64;
    const float4* zl = reinterpret_cast<const float4*>(zps[wid]);
    float a1 = 0.0f, a2 = 0.0f;
#pragma unroll 4
    for (int d = 0; d < 64; ++d) {
        float4 c = zl[d];  // broadcast
        float4 f1 = r1[d];
        float4 f2 = r2[d];
        a1 += f1.x * c.x + f1.y * c.y + f1.z * c.z + f1.w * c.w;
        a2 += f2.x * c.x + f2.y * c.y + f2.z * c.z + f2.w * c.w;
    }
    float l1 = a1 * TEMP_INV, l2 = a2 * TEMP_INV;

    // logsumexp over {pos, 128 negs}
    float m = fmaxf(l1, l2);
#pragma unroll
    for (int off = 32; off; off >>= 1) m = fmaxf(m, __shfl_xor(m, off, 64));
    m = fmaxf(m, pos);
    float e = __expf(l1 - m) + __expf(l2 - m);
#pragma unroll
    for (int off = 32; off; off >>= 1) e += __shfl_xor(e, off, 64);
    e += __expf(pos - m);
    float lse = m + __logf(e);
    if (lane == 0) atomicAdd(out, (lse - pos) * scale);
}

extern "C" void kernel_launch(void* const* d_in, const int* in_sizes, int n_in,
                              void* d_out, int out_size, void* d_ws, size_t ws_size,
                              hipStream_t stream) {
    const float* z     = (const float*)d_in[0];  // (16,512,256) fp32
    const float* preds = (const float*)d_in[1];  // (3,256,256) fp32
    const int*   nidx  = (const int*)d_in[2];    // (3,8192,128) int32
    float* out = (float*)d_out;
    float* all_z = (float*)d_ws;
    float* zp    = all_z + (size_t)BTc * Dc;

    k_zero<<<1, 1, 0, stream>>>(out);
    k_norm<<<BTc / 4, 256, 0, stream>>>(z, all_z);

    const int ks[3] = {1, 5, 21};
    double rw[3] = {1.0, 1.0 / sqrt(5.0), 1.0 / sqrt(21.0)};
    double tot = rw[0] + rw[1] + rw[2];
    for (int i = 0; i < 3; ++i) {
        int L = Tc - ks[i], N = Bc * L;
        float scale = (float)(rw[i] / tot / (double)N);
        k_pred<<<(N + 31) / 32, 256, 0, stream>>>(z, preds + (size_t)i * Dc * Dc, zp, L, N);
        k_loss<<<(N + 3) / 4, 256, 0, stream>>>(all_z, zp, nidx + (size_t)i * BTc * NNEGc,
                                                out, L, N, ks[i], scale);
    }
}

// Round 2
// 316.926 us; speedup vs baseline: 2.4838x; 2.4838x over previous
//
#include <hip/hip_runtime.h>
#include <math.h>

// CPC loss, MI355X. B=16 T=512 D=256, horizons {1,5,21}, 128 negatives, temp 0.07.
constexpr int Bc = 16, Tc = 512, Dc = 256, NNEGc = 128, BTc = Bc * Tc;
constexpr float TEMP_INV = 1.0f / 0.07f;
constexpr float NEG_INF = -3.0e38f;

struct HP { int L, N, kh, wOff; float scale; long long zpOff, nxOff; };
struct HP3 { HP h[3]; };

__device__ inline float blo(unsigned u) { union { unsigned i; float f; } c; c.i = u << 16; return c.f; }
__device__ inline float bhi(unsigned u) { union { unsigned i; float f; } c; c.i = u & 0xffff0000u; return c.f; }
__device__ inline unsigned f2bf(float f) {  // RNE round to bf16, return in low 16
    union { float f; unsigned u; } c; c.f = f;
    return (c.u + 0x7fffu + ((c.u >> 16) & 1u)) >> 16;
}

// Normalize all BT rows -> packed bf16 table (row = 128 uint32 = 512 B). Also zeroes out[0].
__global__ __launch_bounds__(256) void k_norm(const float* __restrict__ z,
                                              unsigned* __restrict__ az,
                                              float* __restrict__ out) {
    if (blockIdx.x == 0 && threadIdx.x == 0) out[0] = 0.0f;
    int wid = threadIdx.x >> 6, lane = threadIdx.x & 63;
    int row = blockIdx.x * 4 + wid;  // grid = BT/4
    float4 v = reinterpret_cast<const float4*>(z)[row * 64 + lane];
    float s = v.x * v.x + v.y * v.y + v.z * v.z + v.w * v.w;
#pragma unroll
    for (int off = 32; off; off >>= 1) s += __shfl_xor(s, off, 64);
    float inv = 1.0f / fmaxf(sqrtf(s), 1e-12f);
    unsigned p0 = f2bf(v.x * inv) | (f2bf(v.y * inv) << 16);
    unsigned p1 = f2bf(v.z * inv) | (f2bf(v.w * inv) << 16);
    reinterpret_cast<uint2*>(az)[row * 64 + lane] = make_uint2(p0, p1);
}

// z_pred[n][e] = sum_d z[src(n)][d] * W[e*256+d].  No LDS: A-row values are
// wave-uniform -> SGPR broadcast (readfirstlane); thread t = column e=t,
// 32 rows per block, acc[32]. grid = (ceil(N/32), nHorizons).
__global__ __launch_bounds__(256) void k_pred(const float* __restrict__ z,
                                              const float* __restrict__ preds,
                                              float* __restrict__ zp_base,
                                              HP3 P) {
    HP hp = P.h[blockIdx.y];
    int n0 = blockIdx.x * 32;
    int t = threadIdx.x;
    int roff[32];
#pragma unroll
    for (int r = 0; r < 32; ++r) {
        int n = n0 + r; if (n >= hp.N) n = hp.N - 1;
        int b = n / hp.L, l = n - b * hp.L;
        roff[r] = __builtin_amdgcn_readfirstlane((b * Tc + l) * Dc);
    }
    float acc[32];
#pragma unroll
    for (int r = 0; r < 32; ++r) acc[r] = 0.0f;
    const float* Wrow = preds + hp.wOff + t * Dc;
    for (int k8 = 0; k8 < 32; ++k8) {
        float4 w0 = reinterpret_cast<const float4*>(Wrow)[k8 * 2];
        float4 w1 = reinterpret_cast<const float4*>(Wrow)[k8 * 2 + 1];
#pragma unroll
        for (int r = 0; r < 32; ++r) {
            const float* a = z + roff[r] + k8 * 8;  // uniform -> s_load
            acc[r] += a[0] * w0.x + a[1] * w0.y + a[2] * w0.z + a[3] * w0.w
                    + a[4] * w1.x + a[5] * w1.y + a[6] * w1.z + a[7] * w1.w;
        }
    }
    float* zp = zp_base + hp.zpOff;
#pragma unroll
    for (int r = 0; r < 32; ++r) {
        int n = n0 + r;
        if (n < hp.N) zp[(size_t)n * Dc + t] = acc[r];
    }
}

// One wave per row n. Quad-cooperative gather: quad q handles negative j=p*16+q
// per pass p (8 passes); 4 lanes x 16B = 64B contiguous per instr (coalesced).
// z_pred fragments hoisted to registers; online logsumexp; 1 atomic per block.
__global__ __launch_bounds__(256) void k_loss(const unsigned* __restrict__ az,
                                              const float* __restrict__ zp_base,
                                              const int* __restrict__ nx_base,
                                              float* __restrict__ out,
                                              HP3 P) {
    HP hp = P.h[blockIdx.y];
    __shared__ float zps[4][Dc];
    __shared__ float partial[4];
    int wid = threadIdx.x >> 6, lane = threadIdx.x & 63;
    int q = lane >> 2, q4 = lane & 3;
    int n = blockIdx.x * 4 + wid;
    float contrib = 0.0f;
    if (n < hp.N) {
        const float* zp = zp_base + hp.zpOff + (size_t)n * Dc;
        float4 v = reinterpret_cast<const float4*>(zp)[lane];
        float s = v.x * v.x + v.y * v.y + v.z * v.z + v.w * v.w;
#pragma unroll
        for (int off = 32; off; off >>= 1) s += __shfl_xor(s, off, 64);
        float inv = 1.0f / fmaxf(sqrtf(s), 1e-12f);
        v.x *= inv; v.y *= inv; v.z *= inv; v.w *= inv;
        reinterpret_cast<float4*>(zps[wid])[lane] = v;

        // positive logit (bf16 target row)
        int b = n / hp.L, l = n - b * hp.L;
        int mrow = b * Tc + l + hp.kh;
        uint2 pw = reinterpret_cast<const uint2*>(az + (size_t)mrow * 128)[lane];
        float pd = blo(pw.x) * v.x + bhi(pw.x) * v.y + blo(pw.y) * v.z + bhi(pw.y) * v.w;
#pragma unroll
        for (int off = 32; off; off >>= 1) pd += __shfl_xor(pd, off, 64);
        float pos = pd * TEMP_INV;

        // hoist this row's z_pred into registers: chunk c = elems [c*32+q4*8, +8)
        float4 zr[8][2];
        const float4* zl4 = reinterpret_cast<const float4*>(zps[wid]);
#pragma unroll
        for (int c = 0; c < 8; ++c) {
            int fidx = c * 8 + q4 * 2;
            zr[c][0] = zl4[fidx];
            zr[c][1] = zl4[fidx + 1];
        }

        const int* nx = nx_base + hp.nxOff + (size_t)n * NNEGc;
        int i1 = nx[lane], i2 = nx[lane + 64];
        float mrun = NEG_INF, srun = 0.0f;
#pragma unroll
        for (int p = 0; p < 8; ++p) {
            int src = (p & 3) * 16 + q;
            int idx = __shfl(p < 4 ? i1 : i2, src, 64);
            const uint4* nr = reinterpret_cast<const uint4*>(az + (size_t)idx * 128);
            float a = 0.0f;
#pragma unroll
            for (int c = 0; c < 8; ++c) {
                uint4 g = nr[c * 4 + q4];
                a += blo(g.x) * zr[c][0].x + bhi(g.x) * zr[c][0].y
                   + blo(g.y) * zr[c][0].z + bhi(g.y) * zr[c][0].w
                   + blo(g.z) * zr[c][1].x + bhi(g.z) * zr[c][1].y
                   + blo(g.w) * zr[c][1].z + bhi(g.w) * zr[c][1].w;
            }
            a += __shfl_xor(a, 1, 64);
            a += __shfl_xor(a, 2, 64);
            float lg = a * TEMP_INV;
            float nm = fmaxf(mrun, lg);
            srun = srun * __expf(mrun - nm) + __expf(lg - nm);
            mrun = nm;
        }
        if (q4 != 0) { mrun = NEG_INF; srun = 0.0f; }  // dedupe quad copies
#pragma unroll
        for (int off = 32; off; off >>= 1) {
            float mo = __shfl_xor(mrun, off, 64), so = __shfl_xor(srun, off, 64);
            float nm = fmaxf(mrun, mo);
            srun = srun * __expf(mrun - nm) + so * __expf(mo - nm);
            mrun = nm;
        }
        float nm = fmaxf(mrun, pos);
        float S = srun * __expf(mrun - nm) + __expf(pos - nm);
        float lse = nm + __logf(S);
        contrib = (lse - pos) * hp.scale;
    }
    if (lane == 0) partial[wid] = contrib;
    __syncthreads();
    if (threadIdx.x == 0)
        atomicAdd(out, partial[0] + partial[1] + partial[2] + partial[3]);
}

extern "C" void kernel_launch(void* const* d_in, const int* in_sizes, int n_in,
                              void* d_out, int out_size, void* d_ws, size_t ws_size,
                              hipStream_t stream) {
    const float* z     = (const float*)d_in[0];
    const float* preds = (const float*)d_in[1];
    const int*   nidx  = (const int*)d_in[2];
    float* out = (float*)d_out;

    unsigned* az = (unsigned*)d_ws;                       // 4 MB bf16 table
    size_t azBytes = (size_t)BTc * Dc * 2;
    float* zp_base = (float*)((char*)d_ws + azBytes);
    size_t zpStride = (size_t)BTc * Dc;                   // floats per horizon

    const int ks[3] = {1, 5, 21};
    double rw[3] = {1.0, 1.0 / sqrt(5.0), 1.0 / sqrt(21.0)};
    double tot = rw[0] + rw[1] + rw[2];

    bool fused = ws_size >= azBytes + 3 * zpStride * sizeof(float);

    k_norm<<<BTc / 4, 256, 0, stream>>>(z, az, out);

    if (fused) {
        HP3 P;
        int maxN = 0;
        for (int i = 0; i < 3; ++i) {
            int L = Tc - ks[i], N = Bc * L;
            P.h[i].L = L; P.h[i].N = N; P.h[i].kh = ks[i];
            P.h[i].wOff = i * Dc * Dc;
            P.h[i].scale = (float)(rw[i] / tot / (double)N);
            P.h[i].zpOff = (long long)i * zpStride;
            P.h[i].nxOff = (long long)i * BTc * NNEGc;
            if (N > maxN) maxN = N;
        }
        dim3 gp((maxN + 31) / 32, 3), gl((maxN + 3) / 4, 3);
        k_pred<<<gp, 256, 0, stream>>>(z, preds, zp_base, P);
        k_loss<<<gl, 256, 0, stream>>>(az, zp_base, nidx, out, P);
    } else {
        for (int i = 0; i < 3; ++i) {
            int L = Tc - ks[i], N = Bc * L;
            HP3 P;
            P.h[0].L = L; P.h[0].N = N; P.h[0].kh = ks[i];
            P.h[0].wOff = i * Dc * Dc;
            P.h[0].scale = (float)(rw[i] / tot / (double)N);
            P.h[0].zpOff = 0;
            P.h[0].nxOff = (long long)i * BTc * NNEGc;
            k_pred<<<dim3((N + 31) / 32, 1), 256, 0, stream>>>(z, preds, zp_base, P);
            k_loss<<<dim3((N + 3) / 4, 1), 256, 0, stream>>>(az, zp_base, nidx, out, P);
        }
    }
}

// Round 3
// 190.342 us; speedup vs baseline: 4.1356x; 1.6650x over previous
//
#include <hip/hip_runtime.h>
#include <math.h>

// CPC loss, MI355X. B=16 T=512 D=256, horizons {1,5,21}, 128 negatives, temp 0.07.
// ws: [0,4MB) az bf16 table | [4MB,+384KB) Wbf bf16 | [4.375MB,+12MB) zp f16 [3][8192][256]
constexpr int Bc = 16, Tc = 512, Dc = 256, NNEGc = 128, BTc = Bc * Tc;
constexpr float TEMP_INV = 1.0f / 0.07f;
constexpr float NEG_INF = -3.0e38f;

typedef __attribute__((ext_vector_type(8))) short short8;
typedef __attribute__((ext_vector_type(4))) float f32x4;
typedef __attribute__((ext_vector_type(4))) _Float16 f16x4;

struct HP { int L, N, kh; float scale; long long nxOff; };
struct HP3 { HP h[3]; };

__device__ inline float blo(unsigned u) { union { unsigned i; float f; } c; c.i = u << 16; return c.f; }
__device__ inline float bhi(unsigned u) { union { unsigned i; float f; } c; c.i = u & 0xffff0000u; return c.f; }
__device__ inline unsigned f2bf(float f) {  // RNE to bf16, low 16 bits
    union { float f; unsigned u; } c; c.f = f;
    return (c.u + 0x7fffu + ((c.u >> 16) & 1u)) >> 16;
}

// Normalize all BT rows -> packed bf16 table; first 96 blocks also convert W to bf16;
// block 0 zeroes out[0].
__global__ __launch_bounds__(256) void k_norm(const float* __restrict__ z,
                                              const float* __restrict__ preds,
                                              unsigned* __restrict__ az,
                                              unsigned* __restrict__ Wbf,
                                              float* __restrict__ out) {
    if (blockIdx.x == 0 && threadIdx.x == 0) out[0] = 0.0f;
    if (blockIdx.x < 96) {  // 96*256*8 = 196608 = 3*256*256 floats of W
        int base = blockIdx.x * 2048 + threadIdx.x * 8;
        float4 w0 = reinterpret_cast<const float4*>(preds + base)[0];
        float4 w1 = reinterpret_cast<const float4*>(preds + base)[1];
        uint4 o;
        o.x = f2bf(w0.x) | (f2bf(w0.y) << 16);
        o.y = f2bf(w0.z) | (f2bf(w0.w) << 16);
        o.z = f2bf(w1.x) | (f2bf(w1.y) << 16);
        o.w = f2bf(w1.z) | (f2bf(w1.w) << 16);
        reinterpret_cast<uint4*>(Wbf)[blockIdx.x * 256 + threadIdx.x] = o;
    }
    int wid = threadIdx.x >> 6, lane = threadIdx.x & 63;
    int row = blockIdx.x * 4 + wid;  // grid = BT/4 = 2048
    float4 v = reinterpret_cast<const float4*>(z)[row * 64 + lane];
    float s = v.x * v.x + v.y * v.y + v.z * v.z + v.w * v.w;
#pragma unroll
    for (int off = 32; off; off >>= 1) s += __shfl_xor(s, off, 64);
    float inv = 1.0f / fmaxf(sqrtf(s), 1e-12f);
    unsigned p0 = f2bf(v.x * inv) | (f2bf(v.y * inv) << 16);
    unsigned p1 = f2bf(v.z * inv) | (f2bf(v.w * inv) << 16);
    reinterpret_cast<uint2*>(az)[row * 64 + lane] = make_uint2(p0, p1);
}

// Fused GEMM: zp[h][m][e] = sum_d az[m][d] * W[h][e][d], bf16 MFMA 16x16x32.
// Wave = 16 rows x 64 cols; A/B frags loaded straight from global (frag = 8
// contiguous k = one uint4; 16 fully-consumed 64B lines per load instr).
// grid = (8192/64, 768/64), block = 256 (4 waves).
__global__ __launch_bounds__(256) void k_gemm(const unsigned* __restrict__ az,
                                              const unsigned* __restrict__ Wbf,
                                              _Float16* __restrict__ zp) {
    int wave = threadIdx.x >> 6, lane = threadIdx.x & 63;
    int m0 = blockIdx.x * 64 + wave * 16;
    int g0 = blockIdx.y * 64;
    int mrow = lane & 15;   // A row / B col within tile
    int kq = lane >> 4;     // k-quad: k = kb*32 + kq*8 + j
    const uint4* A4 = reinterpret_cast<const uint4*>(az);
    const uint4* B4 = reinterpret_cast<const uint4*>(Wbf);
    f32x4 acc[4] = {f32x4{0,0,0,0}, f32x4{0,0,0,0}, f32x4{0,0,0,0}, f32x4{0,0,0,0}};
    size_t arow = (size_t)(m0 + mrow) * 32 + kq;
#pragma unroll
    for (int kb = 0; kb < 8; ++kb) {
        uint4 ua = A4[arow + kb * 4];
        short8 a = __builtin_bit_cast(short8, ua);
#pragma unroll
        for (int nt = 0; nt < 4; ++nt) {
            uint4 ub = B4[(size_t)(g0 + nt * 16 + mrow) * 32 + kb * 4 + kq];
            acc[nt] = __builtin_amdgcn_mfma_f32_16x16x32_bf16(
                a, __builtin_bit_cast(short8, ub), acc[nt], 0, 0, 0);
        }
    }
    // C/D layout: col = lane&15, row = kq*4 + r
#pragma unroll
    for (int nt = 0; nt < 4; ++nt) {
        int g = g0 + nt * 16 + mrow;
        int h = g >> 8, e = g & 255;
        _Float16* dst = zp + ((size_t)h * BTc + m0 + kq * 4) * Dc + e;
#pragma unroll
        for (int r = 0; r < 3 + 1; ++r) dst[(size_t)r * Dc] = (_Float16)acc[nt][r];
    }
}

// One wave per row n. Quad-coop gather (quad q -> negative p*16+q, 4 lanes x 16B
// = one 64B line per row-chunk). Deferred softmax: 8 independent lg[p], then one
// max/exp-sum reduce. 1 atomic per block.
__global__ __launch_bounds__(256) void k_loss(const unsigned* __restrict__ az,
                                              const _Float16* __restrict__ zp_base,
                                              const int* __restrict__ nx_base,
                                              float* __restrict__ out,
                                              HP3 P) {
    HP hp = P.h[blockIdx.y];
    __shared__ float zps[4][Dc];
    __shared__ float partial[4];
    int wid = threadIdx.x >> 6, lane = threadIdx.x & 63;
    int q = lane >> 2, q4 = lane & 3;
    int n = blockIdx.x * 4 + wid;
    float contrib = 0.0f;
    if (n < hp.N) {
        int b = n / hp.L, l = n - b * hp.L;
        int row = b * Tc + l;
        // normalize z_pred row (f16) into LDS
        f16x4 hv = reinterpret_cast<const f16x4*>(
                       zp_base + ((size_t)blockIdx.y * BTc + row) * Dc)[lane];
        float4 v = make_float4((float)hv.x, (float)hv.y, (float)hv.z, (float)hv.w);
        float s = v.x * v.x + v.y * v.y + v.z * v.z + v.w * v.w;
#pragma unroll
        for (int off = 32; off; off >>= 1) s += __shfl_xor(s, off, 64);
        float inv = 1.0f / fmaxf(sqrtf(s), 1e-12f);
        v.x *= inv; v.y *= inv; v.z *= inv; v.w *= inv;
        reinterpret_cast<float4*>(zps[wid])[lane] = v;

        // positive logit
        uint2 pw = reinterpret_cast<const uint2*>(az + (size_t)(row + hp.kh) * 128)[lane];
        float pd = blo(pw.x) * v.x + bhi(pw.x) * v.y + blo(pw.y) * v.z + bhi(pw.y) * v.w;
#pragma unroll
        for (int off = 32; off; off >>= 1) pd += __shfl_xor(pd, off, 64);
        float pos = pd * TEMP_INV;

        // hoist z_pred quad-view into registers: chunk c = elems [c*32+q4*8, +8)
        float4 zr[8][2];
        const float4* zl4 = reinterpret_cast<const float4*>(zps[wid]);
#pragma unroll
        for (int c = 0; c < 8; ++c) {
            zr[c][0] = zl4[c * 8 + q4 * 2];
            zr[c][1] = zl4[c * 8 + q4 * 2 + 1];
        }

        const int* nx = nx_base + hp.nxOff + (size_t)n * NNEGc;
        int i1 = nx[lane], i2 = nx[lane + 64];
        float lg[8];
#pragma unroll
        for (int p = 0; p < 8; ++p) {
            int src = (p & 3) * 16 + q;
            int idx = __shfl(p < 4 ? i1 : i2, src, 64);
            const uint4* nr = reinterpret_cast<const uint4*>(az + (size_t)idx * 128);
            float a = 0.0f;
#pragma unroll
            for (int c = 0; c < 8; ++c) {
                uint4 g = nr[c * 4 + q4];
                a += blo(g.x) * zr[c][0].x + bhi(g.x) * zr[c][0].y
                   + blo(g.y) * zr[c][0].z + bhi(g.y) * zr[c][0].w
                   + blo(g.z) * zr[c][1].x + bhi(g.z) * zr[c][1].y
                   + blo(g.w) * zr[c][1].z + bhi(g.w) * zr[c][1].w;
            }
            a += __shfl_xor(a, 1, 64);
            a += __shfl_xor(a, 2, 64);
            lg[p] = a * TEMP_INV;
        }
        float mm = lg[0];
#pragma unroll
        for (int p = 1; p < 8; ++p) mm = fmaxf(mm, lg[p]);
#pragma unroll
        for (int off = 32; off; off >>= 1) mm = fmaxf(mm, __shfl_xor(mm, off, 64));
        mm = fmaxf(mm, pos);
        float sl = 0.0f;
#pragma unroll
        for (int p = 0; p < 8; ++p) sl += __expf(lg[p] - mm);
#pragma unroll
        for (int off = 32; off; off >>= 1) sl += __shfl_xor(sl, off, 64);
        float S = sl * 0.25f + __expf(pos - mm);  // each neg replicated 4x in quad
        float lse = mm + __logf(S);
        contrib = (lse - pos) * hp.scale;
    }
    if (lane == 0) partial[wid] = contrib;
    __syncthreads();
    if (threadIdx.x == 0)
        atomicAdd(out, partial[0] + partial[1] + partial[2] + partial[3]);
}

extern "C" void kernel_launch(void* const* d_in, const int* in_sizes, int n_in,
                              void* d_out, int out_size, void* d_ws, size_t ws_size,
                              hipStream_t stream) {
    const float* z     = (const float*)d_in[0];
    const float* preds = (const float*)d_in[1];
    const int*   nidx  = (const int*)d_in[2];
    float* out = (float*)d_out;

    unsigned* az  = (unsigned*)d_ws;                                   // 4 MB
    unsigned* Wbf = (unsigned*)((char*)d_ws + (size_t)4194304);        // 384 KB
    _Float16* zp  = (_Float16*)((char*)d_ws + (size_t)4587520);       // 12 MB

    const int ks[3] = {1, 5, 21};
    double rw[3] = {1.0, 1.0 / sqrt(5.0), 1.0 / sqrt(21.0)};
    double tot = rw[0] + rw[1] + rw[2];

    HP3 P;
    int maxN = 0;
    for (int i = 0; i < 3; ++i) {
        int L = Tc - ks[i], N = Bc * L;
        P.h[i].L = L; P.h[i].N = N; P.h[i].kh = ks[i];
        P.h[i].scale = (float)(rw[i] / tot / (double)N);
        P.h[i].nxOff = (long long)i * BTc * NNEGc;
        if (N > maxN) maxN = N;
    }

    k_norm<<<BTc / 4, 256, 0, stream>>>(z, preds, az, Wbf, out);
    k_gemm<<<dim3(BTc / 64, (3 * Dc) / 64), 256, 0, stream>>>(az, Wbf, zp);
    k_loss<<<dim3((maxN + 3) / 4, 3), 256, 0, stream>>>(az, zp, nidx, out, P);
}

// Round 4
// 177.346 us; speedup vs baseline: 4.4386x; 1.0733x over previous
//
#include <hip/hip_runtime.h>
#include <math.h>

// CPC loss, MI355X. B=16 T=512 D=256, horizons {1,5,21}, 128 negatives, temp 0.07.
// ws: [0,4MB) az f16 table | [4MB,+384KB) Wh f16 | [4.375MB,+12MB) zp f16 [3][8192][256]
constexpr int Bc = 16, Tc = 512, Dc = 256, NNEGc = 128, BTc = Bc * Tc;
constexpr float TEMP_INV = 1.0f / 0.07f;

typedef __attribute__((ext_vector_type(8))) short short8;
typedef __attribute__((ext_vector_type(4))) float f32x4;
typedef __attribute__((ext_vector_type(4))) _Float16 f16x4;
typedef __attribute__((ext_vector_type(2))) _Float16 h2;

struct HP { int L, N, kh; float scale; long long nxOff; };
struct HP3 { HP h[3]; };

__device__ inline unsigned packh2(float a, float b) {
    h2 p = {(_Float16)a, (_Float16)b};
    return __builtin_bit_cast(unsigned, p);
}
__device__ inline float dot2(unsigned a, unsigned b, float c) {
#if __has_builtin(__builtin_amdgcn_fdot2)
    return __builtin_amdgcn_fdot2(__builtin_bit_cast(h2, a), __builtin_bit_cast(h2, b), c, false);
#else
    h2 x = __builtin_bit_cast(h2, a), y = __builtin_bit_cast(h2, b);
    return c + (float)x.x * (float)y.x + (float)x.y * (float)y.y;
#endif
}

// Normalize all BT rows -> packed f16 table; first 96 blocks also convert W to f16;
// block 0 zeroes out[0].
__global__ __launch_bounds__(256) void k_norm(const float* __restrict__ z,
                                              const float* __restrict__ preds,
                                              unsigned* __restrict__ az,
                                              unsigned* __restrict__ Wh,
                                              float* __restrict__ out) {
    if (blockIdx.x == 0 && threadIdx.x == 0) out[0] = 0.0f;
    if (blockIdx.x < 96) {  // 96*256*8 = 196608 = 3*256*256 floats of W
        int base = blockIdx.x * 2048 + threadIdx.x * 8;
        float4 w0 = reinterpret_cast<const float4*>(preds + base)[0];
        float4 w1 = reinterpret_cast<const float4*>(preds + base)[1];
        uint4 o;
        o.x = packh2(w0.x, w0.y); o.y = packh2(w0.z, w0.w);
        o.z = packh2(w1.x, w1.y); o.w = packh2(w1.z, w1.w);
        reinterpret_cast<uint4*>(Wh)[blockIdx.x * 256 + threadIdx.x] = o;
    }
    int wid = threadIdx.x >> 6, lane = threadIdx.x & 63;
    int row = blockIdx.x * 4 + wid;  // grid = BT/4 = 2048
    float4 v = reinterpret_cast<const float4*>(z)[row * 64 + lane];
    float s = v.x * v.x + v.y * v.y + v.z * v.z + v.w * v.w;
#pragma unroll
    for (int off = 32; off; off >>= 1) s += __shfl_xor(s, off, 64);
    float inv = 1.0f / fmaxf(sqrtf(s), 1e-12f);
    reinterpret_cast<uint2*>(az)[row * 64 + lane] =
        make_uint2(packh2(v.x * inv, v.y * inv), packh2(v.z * inv, v.w * inv));
}

// LDS-tiled f16 MFMA GEMM: zp[h][m][e] = sum_d az[m][d] * W[h][e][d].
// Block = 64 M-rows x 64 N-cols, K=256 in one pass. A/B tiles are CONTIGUOUS
// 32 KB regions of az/Wh -> fully coalesced staging, then ds_read_b128 frags.
// grid = (8192/64, 768/64), block = 256 (4 waves; wave w owns M-rows w*16..+16).
__global__ __launch_bounds__(256) void k_gemm(const unsigned* __restrict__ az,
                                              const unsigned* __restrict__ Wh,
                                              _Float16* __restrict__ zp) {
    __shared__ uint4 As[2048];  // 64 rows x 512 B
    __shared__ uint4 Bs[2048];
    int wave = threadIdx.x >> 6, lane = threadIdx.x & 63;
    int t = threadIdx.x;
    int m0 = blockIdx.x * 64;
    int g0 = blockIdx.y * 64;
    const uint4* A4 = reinterpret_cast<const uint4*>(az) + (size_t)m0 * 32;
    const uint4* B4 = reinterpret_cast<const uint4*>(Wh) + (size_t)g0 * 32;
#pragma unroll
    for (int i = 0; i < 8; ++i) {
        As[i * 256 + t] = A4[i * 256 + t];
        Bs[i * 256 + t] = B4[i * 256 + t];
    }
    __syncthreads();
    int mrow = lane & 15, kq = lane >> 4;
    f32x4 acc[4] = {f32x4{0,0,0,0}, f32x4{0,0,0,0}, f32x4{0,0,0,0}, f32x4{0,0,0,0}};
#pragma unroll
    for (int kb = 0; kb < 8; ++kb) {
        uint4 ua = As[(wave * 16 + mrow) * 32 + kb * 4 + kq];
        short8 a = __builtin_bit_cast(short8, ua);
#pragma unroll
        for (int nt = 0; nt < 4; ++nt) {
            uint4 ub = Bs[(nt * 16 + mrow) * 32 + kb * 4 + kq];
            acc[nt] = __builtin_amdgcn_mfma_f32_16x16x32_f16(
                a, __builtin_bit_cast(short8, ub), acc[nt], 0, 0, 0);
        }
    }
    // C/D layout: col(=g) = lane&15, row(=m offset) = kq*4 + r
#pragma unroll
    for (int nt = 0; nt < 4; ++nt) {
        int g = g0 + nt * 16 + mrow;
        int h = g >> 8, e = g & 255;
        _Float16* dst = zp + ((size_t)h * BTc + m0 + wave * 16 + kq * 4) * Dc + e;
#pragma unroll
        for (int r = 0; r < 4; ++r) dst[(size_t)r * Dc] = (_Float16)acc[nt][r];
    }
}

// One wave per row n. Quad-coop gather (quad q -> negative p*16+q; 4 lanes x 16B
// = one 64B line per 32-elem chunk). f16 pairs + v_dot2_f32_f16. Deferred
// softmax. 1 atomic per block.
__global__ __launch_bounds__(256) void k_loss(const unsigned* __restrict__ az,
                                              const _Float16* __restrict__ zp_base,
                                              const int* __restrict__ nx_base,
                                              float* __restrict__ out,
                                              HP3 P) {
    HP hp = P.h[blockIdx.y];
    __shared__ unsigned zps[4][128];  // packed f16 pairs, per wave
    __shared__ float partial[4];
    int wid = threadIdx.x >> 6, lane = threadIdx.x & 63;
    int q = lane >> 2, q4 = lane & 3;
    int n = blockIdx.x * 4 + wid;
    float contrib = 0.0f;
    if (n < hp.N) {
        int b = n / hp.L, l = n - b * hp.L;
        int row = b * Tc + l;
        // normalize z_pred row (f16) -> packed f16 into LDS
        f16x4 hv = reinterpret_cast<const f16x4*>(
                       zp_base + ((size_t)blockIdx.y * BTc + row) * Dc)[lane];
        float4 v = make_float4((float)hv.x, (float)hv.y, (float)hv.z, (float)hv.w);
        float s = v.x * v.x + v.y * v.y + v.z * v.z + v.w * v.w;
#pragma unroll
        for (int off = 32; off; off >>= 1) s += __shfl_xor(s, off, 64);
        float inv = 1.0f / fmaxf(sqrtf(s), 1e-12f);
        unsigned u0 = packh2(v.x * inv, v.y * inv);
        unsigned u1 = packh2(v.z * inv, v.w * inv);
        zps[wid][lane * 2] = u0;
        zps[wid][lane * 2 + 1] = u1;

        // positive logit
        uint2 pw = reinterpret_cast<const uint2*>(az + (size_t)(row + hp.kh) * 128)[lane];
        float pd = dot2(pw.y, u1, dot2(pw.x, u0, 0.0f));
#pragma unroll
        for (int off = 32; off; off >>= 1) pd += __shfl_xor(pd, off, 64);
        float pos = pd * TEMP_INV;

        // hoist quad-view of z_pred: chunk c = elems [c*32 + q4*8, +8) (packed)
        uint4 zr[8];
        const uint4* zl4 = reinterpret_cast<const uint4*>(zps[wid]);
#pragma unroll
        for (int c = 0; c < 8; ++c) zr[c] = zl4[c * 4 + q4];

        const int* nx = nx_base + hp.nxOff + (size_t)n * NNEGc;
        int i1 = nx[lane], i2 = nx[lane + 64];
        float lg[8];
#pragma unroll
        for (int p = 0; p < 8; ++p) {
            int src = (p & 3) * 16 + q;
            int idx = __shfl(p < 4 ? i1 : i2, src, 64);
            const uint4* nr = reinterpret_cast<const uint4*>(az + (size_t)idx * 128);
            float a = 0.0f;
#pragma unroll
            for (int c = 0; c < 8; ++c) {
                uint4 g = nr[c * 4 + q4];
                a = dot2(g.x, zr[c].x, a);
                a = dot2(g.y, zr[c].y, a);
                a = dot2(g.z, zr[c].z, a);
                a = dot2(g.w, zr[c].w, a);
            }
            a += __shfl_xor(a, 1, 64);
            a += __shfl_xor(a, 2, 64);
            lg[p] = a * TEMP_INV;
        }
        float mm = lg[0];
#pragma unroll
        for (int p = 1; p < 8; ++p) mm = fmaxf(mm, lg[p]);
#pragma unroll
        for (int off = 32; off; off >>= 1) mm = fmaxf(mm, __shfl_xor(mm, off, 64));
        mm = fmaxf(mm, pos);
        float sl = 0.0f;
#pragma unroll
        for (int p = 0; p < 8; ++p) sl += __expf(lg[p] - mm);
#pragma unroll
        for (int off = 32; off; off >>= 1) sl += __shfl_xor(sl, off, 64);
        float S = sl * 0.25f + __expf(pos - mm);  // each neg replicated 4x in quad
        float lse = mm + __logf(S);
        contrib = (lse - pos) * hp.scale;
    }
    if (lane == 0) partial[wid] = contrib;
    __syncthreads();
    if (threadIdx.x == 0)
        atomicAdd(out, partial[0] + partial[1] + partial[2] + partial[3]);
}

extern "C" void kernel_launch(void* const* d_in, const int* in_sizes, int n_in,
                              void* d_out, int out_size, void* d_ws, size_t ws_size,
                              hipStream_t stream) {
    const float* z     = (const float*)d_in[0];
    const float* preds = (const float*)d_in[1];
    const int*   nidx  = (const int*)d_in[2];
    float* out = (float*)d_out;

    unsigned* az = (unsigned*)d_ws;                                  // 4 MB
    unsigned* Wh = (unsigned*)((char*)d_ws + (size_t)4194304);       // 384 KB
    _Float16* zp = (_Float16*)((char*)d_ws + (size_t)4587520);       // 12 MB

    const int ks[3] = {1, 5, 21};
    double rw[3] = {1.0, 1.0 / sqrt(5.0), 1.0 / sqrt(21.0)};
    double tot = rw[0] + rw[1] + rw[2];

    HP3 P;
    int maxN = 0;
    for (int i = 0; i < 3; ++i) {
        int L = Tc - ks[i], N = Bc * L;
        P.h[i].L = L; P.h[i].N = N; P.h[i].kh = ks[i];
        P.h[i].scale = (float)(rw[i] / tot / (double)N);
        P.h[i].nxOff = (long long)i * BTc * NNEGc;
        if (N > maxN) maxN = N;
    }

    k_norm<<<BTc / 4, 256, 0, stream>>>(z, preds, az, Wh, out);
    k_gemm<<<dim3(BTc / 64, (3 * Dc) / 64), 256, 0, stream>>>(az, Wh, zp);
    k_loss<<<dim3((maxN + 3) / 4, 3), 256, 0, stream>>>(az, zp, nidx, out, P);
}

// Round 6
// 163.065 us; speedup vs baseline: 4.8274x; 1.0876x over previous
//
#include <hip/hip_runtime.h>
#include <math.h>

// CPC loss, MI355X. B=16 T=512 D=256, horizons {1,5,21}, 128 negatives, temp 0.07.
// ws: [0,4MB) az f16 | [4MB,+2MB) anf fp8 | [6MB,+384KB) Wh f16 | [6.375MB,+12MB) zp f16
constexpr int Bc = 16, Tc = 512, Dc = 256, NNEGc = 128, BTc = Bc * Tc;
constexpr float TEMP_INV = 1.0f / 0.07f;

typedef __attribute__((ext_vector_type(8))) short short8;
typedef __attribute__((ext_vector_type(4))) float f32x4;
typedef __attribute__((ext_vector_type(2))) float f32x2;
typedef __attribute__((ext_vector_type(4))) _Float16 f16x4;
typedef __attribute__((ext_vector_type(2))) _Float16 h2;

struct HP { int L, N, kh; float scale; long long nxOff; };
struct HP3 { HP h[3]; };

__device__ inline unsigned packh2(float a, float b) {
    h2 p = {(_Float16)a, (_Float16)b};
    return __builtin_bit_cast(unsigned, p);
}
__device__ inline float dot2(unsigned a, unsigned b, float c) {
#if __has_builtin(__builtin_amdgcn_fdot2)
    return __builtin_amdgcn_fdot2(__builtin_bit_cast(h2, a), __builtin_bit_cast(h2, b), c, false);
#else
    h2 x = __builtin_bit_cast(h2, a), y = __builtin_bit_cast(h2, b);
    return c + (float)x.x * (float)y.x + (float)x.y * (float)y.y;
#endif
}

#if __has_builtin(__builtin_amdgcn_cvt_pk_fp8_f32) && __has_builtin(__builtin_amdgcn_cvt_pk_f32_fp8)
#define HW_FP8 1
#endif
#ifndef HW_FP8
// software e4m3fn fallback (not used on gfx950)
__device__ inline float sw_dec_fp8(unsigned b) {
    unsigned s = b >> 7, e = (b >> 3) & 15, m = b & 7;
    float v = e ? ldexpf(1.0f + m * 0.125f, (int)e - 7) : ldexpf(m * 0.125f, -6);
    return s ? -v : v;
}
__device__ inline unsigned sw_enc_fp8(float x) {
    unsigned s = x < 0.f ? 0x80u : 0u; float a = fabsf(x);
    if (a != a) return 0x7fu;
    if (a < ldexpf(1.f, -10)) return s;
    if (a >= 448.f) return s | 0x7eu;
    int e = (int)floorf(log2f(a)); if (e < -6) e = -6;
    float q = roundf(ldexpf(a, 3 - e));
    if (q >= 16.f) { q *= 0.5f; e += 1; }
    if (e < -6) return s;
    return s | ((unsigned)(e + 7) << 3) | ((unsigned)q & 7u);
}
#endif

// 2 fp8 (template-selected half of u) -> packed f16 pair
template <bool W>
__device__ inline unsigned f8h2(unsigned u) {
#ifdef HW_FP8
    f32x2 f = __builtin_amdgcn_cvt_pk_f32_fp8((int)u, W);
    return __builtin_bit_cast(unsigned, __builtin_amdgcn_cvt_pkrtz(f.x, f.y));
#else
    unsigned v = W ? (u >> 16) : (u & 0xffffu);
    return packh2(sw_dec_fp8(v & 0xffu), sw_dec_fp8(v >> 8));
#endif
}
__device__ inline unsigned enc4_fp8(float a, float b, float c, float d) {
#ifdef HW_FP8
    int lo = __builtin_amdgcn_cvt_pk_fp8_f32(a, b, 0, false);
    return (unsigned)__builtin_amdgcn_cvt_pk_fp8_f32(c, d, lo, true);
#else
    return sw_enc_fp8(a) | (sw_enc_fp8(b) << 8) | (sw_enc_fp8(c) << 16) | (sw_enc_fp8(d) << 24);
#endif
}

// Normalize all BT rows -> az (f16, 512 B/row) + anf (fp8, 256 B/row);
// first 96 blocks also convert W to f16; block 0 zeroes out[0].
__global__ __launch_bounds__(256) void k_norm(const float* __restrict__ z,
                                              const float* __restrict__ preds,
                                              unsigned* __restrict__ az,
                                              unsigned* __restrict__ anf,
                                              unsigned* __restrict__ Wh,
                                              float* __restrict__ out) {
    if (blockIdx.x == 0 && threadIdx.x == 0) out[0] = 0.0f;
    if (blockIdx.x < 96) {
        int base = blockIdx.x * 2048 + threadIdx.x * 8;
        float4 w0 = reinterpret_cast<const float4*>(preds + base)[0];
        float4 w1 = reinterpret_cast<const float4*>(preds + base)[1];
        uint4 o;
        o.x = packh2(w0.x, w0.y); o.y = packh2(w0.z, w0.w);
        o.z = packh2(w1.x, w1.y); o.w = packh2(w1.z, w1.w);
        reinterpret_cast<uint4*>(Wh)[blockIdx.x * 256 + threadIdx.x] = o;
    }
    int wid = threadIdx.x >> 6, lane = threadIdx.x & 63;
    int row = blockIdx.x * 4 + wid;
    float4 v = reinterpret_cast<const float4*>(z)[row * 64 + lane];
    float s = v.x * v.x + v.y * v.y + v.z * v.z + v.w * v.w;
#pragma unroll
    for (int off = 32; off; off >>= 1) s += __shfl_xor(s, off, 64);
    float inv = 1.0f / fmaxf(sqrtf(s), 1e-12f);
    float a = v.x * inv, b = v.y * inv, c = v.z * inv, d = v.w * inv;
    reinterpret_cast<uint2*>(az)[row * 64 + lane] = make_uint2(packh2(a, b), packh2(c, d));
    anf[row * 64 + lane] = enc4_fp8(a, b, c, d);
}

// LDS-tiled f16 MFMA GEMM with XOR-swizzled LDS columns (kills the 512B-stride
// 16-way bank conflict: phys_col = col ^ (row&31) -> near-conflict-free).
// Block = 64x64, K=256 one pass. grid = (8192/64, 768/64), 4 waves.
__global__ __launch_bounds__(256) void k_gemm(const unsigned* __restrict__ az,
                                              const unsigned* __restrict__ Wh,
                                              _Float16* __restrict__ zp) {
    __shared__ uint4 As[2048];
    __shared__ uint4 Bs[2048];
    int wave = threadIdx.x >> 6, lane = threadIdx.x & 63;
    int t = threadIdx.x;
    int m0 = blockIdx.x * 64, g0 = blockIdx.y * 64;
    const uint4* A4 = reinterpret_cast<const uint4*>(az) + (size_t)m0 * 32;
    const uint4* B4 = reinterpret_cast<const uint4*>(Wh) + (size_t)g0 * 32;
#pragma unroll
    for (int i = 0; i < 8; ++i) {
        int f = i * 256 + t;
        int r = f >> 5, c = f & 31;
        int sw = r * 32 + ((c ^ r) & 31);
        As[sw] = A4[f];
        Bs[sw] = B4[f];
    }
    __syncthreads();
    int mrow = lane & 15, kq = lane >> 4;
    f32x4 acc[4] = {f32x4{0,0,0,0}, f32x4{0,0,0,0}, f32x4{0,0,0,0}, f32x4{0,0,0,0}};
    int arow = wave * 16 + mrow;
#pragma unroll
    for (int kb = 0; kb < 8; ++kb) {
        int col = kb * 4 + kq;
        uint4 ua = As[arow * 32 + ((col ^ arow) & 31)];
        short8 a = __builtin_bit_cast(short8, ua);
#pragma unroll
        for (int nt = 0; nt < 4; ++nt) {
            int brow = nt * 16 + mrow;
            uint4 ub = Bs[brow * 32 + ((col ^ brow) & 31)];
            acc[nt] = __builtin_amdgcn_mfma_f32_16x16x32_f16(
                a, __builtin_bit_cast(short8, ub), acc[nt], 0, 0, 0);
        }
    }
    // C/D: col(=g) = lane&15, row(=m offset) = kq*4 + r
#pragma unroll
    for (int nt = 0; nt < 4; ++nt) {
        int g = g0 + nt * 16 + mrow;
        int h = g >> 8, e = g & 255;
        _Float16* dst = zp + ((size_t)h * BTc + m0 + wave * 16 + kq * 4) * Dc + e;
#pragma unroll
        for (int r = 0; r < 4; ++r) dst[(size_t)r * Dc] = (_Float16)acc[nt][r];
    }
}

// One wave per row n. Negatives from fp8 table (256 B/row): quad q -> negative
// p*16+q; 4 lanes x uint4 = one 64B line per chunk (4 chunks/row). Manual
// double-buffered gather pipeline (2 passes/buffer). Deferred softmax,
// 1 atomic/block.
__global__ __launch_bounds__(256, 4) void k_loss(const unsigned* __restrict__ az,
                                                 const unsigned* __restrict__ anf,
                                                 const _Float16* __restrict__ zp_base,
                                                 const int* __restrict__ nx_base,
                                                 float* __restrict__ out,
                                                 HP3 P) {
    HP hp = P.h[blockIdx.y];
    __shared__ unsigned zps[4][128];
    __shared__ float partial[4];
    int wid = threadIdx.x >> 6, lane = threadIdx.x & 63;
    int q = lane >> 2, q4 = lane & 3;
    int n = blockIdx.x * 4 + wid;
    float contrib = 0.0f;
    if (n < hp.N) {
        int b = n / hp.L, l = n - b * hp.L;
        int row = b * Tc + l;
        // normalize z_pred row (f16) -> packed f16 in LDS
        f16x4 hv = reinterpret_cast<const f16x4*>(
                       zp_base + ((size_t)blockIdx.y * BTc + row) * Dc)[lane];
        float4 v = make_float4((float)hv.x, (float)hv.y, (float)hv.z, (float)hv.w);
        float s = v.x * v.x + v.y * v.y + v.z * v.z + v.w * v.w;
#pragma unroll
        for (int off = 32; off; off >>= 1) s += __shfl_xor(s, off, 64);
        float inv = 1.0f / fmaxf(sqrtf(s), 1e-12f);
        unsigned u0 = packh2(v.x * inv, v.y * inv);
        unsigned u1 = packh2(v.z * inv, v.w * inv);
        zps[wid][lane * 2] = u0;
        zps[wid][lane * 2 + 1] = u1;

        // positive logit (f16 table)
        uint2 pw = reinterpret_cast<const uint2*>(az + (size_t)(row + hp.kh) * 128)[lane];
        float pd = dot2(pw.y, u1, dot2(pw.x, u0, 0.0f));
#pragma unroll
        for (int off = 32; off; off >>= 1) pd += __shfl_xor(pd, off, 64);
        float pos = pd * TEMP_INV;

        // all 8 gather indices up-front
        const int* nx = nx_base + hp.nxOff + (size_t)n * NNEGc;
        int i1 = nx[lane], i2 = nx[lane + 64];
        int idxp[8];
#pragma unroll
        for (int p = 0; p < 8; ++p)
            idxp[p] = __shfl(p < 4 ? i1 : i2, (p & 3) * 16 + q, 64);

        const uint4* nf4 = reinterpret_cast<const uint4*>(anf);
        const uint4* zl4 = reinterpret_cast<const uint4*>(zps[wid]);
        uint4 gb[2][2][4];
        float lg[8];
#define LOAD_PAIR(buf, p0)                                                   \
        _Pragma("unroll")                                                    \
        for (int pp = 0; pp < 2; ++pp)                                       \
            _Pragma("unroll")                                                \
            for (int c = 0; c < 4; ++c)                                      \
                gb[buf][pp][c] = nf4[(size_t)idxp[(p0) + pp] * 16 + c * 4 + q4];
#define COMP_PAIR(buf, p0)                                                   \
        _Pragma("unroll")                                                    \
        for (int pp = 0; pp < 2; ++pp) {                                     \
            float a = 0.0f;                                                  \
            _Pragma("unroll")                                                \
            for (int c = 0; c < 4; ++c) {                                    \
                uint4 g = gb[buf][pp][c];                                    \
                uint4 za = zl4[c * 8 + q4 * 2];                              \
                uint4 zb = zl4[c * 8 + q4 * 2 + 1];                          \
                a = dot2(f8h2<false>(g.x), za.x, a);                         \
                a = dot2(f8h2<true>(g.x),  za.y, a);                         \
                a = dot2(f8h2<false>(g.y), za.z, a);                         \
                a = dot2(f8h2<true>(g.y),  za.w, a);                         \
                a = dot2(f8h2<false>(g.z), zb.x, a);                         \
                a = dot2(f8h2<true>(g.z),  zb.y, a);                         \
                a = dot2(f8h2<false>(g.w), zb.z, a);                         \
                a = dot2(f8h2<true>(g.w),  zb.w, a);                         \
            }                                                                \
            a += __shfl_xor(a, 1, 64);                                       \
            a += __shfl_xor(a, 2, 64);                                       \
            lg[(p0) + pp] = a * TEMP_INV;                                    \
        }
        LOAD_PAIR(0, 0)
        LOAD_PAIR(1, 2)
        COMP_PAIR(0, 0)
        LOAD_PAIR(0, 4)
        COMP_PAIR(1, 2)
        LOAD_PAIR(1, 6)
        COMP_PAIR(0, 4)
        COMP_PAIR(1, 6)
#undef LOAD_PAIR
#undef COMP_PAIR
        float mm = lg[0];
#pragma unroll
        for (int p = 1; p < 8; ++p) mm = fmaxf(mm, lg[p]);
#pragma unroll
        for (int off = 32; off; off >>= 1) mm = fmaxf(mm, __shfl_xor(mm, off, 64));
        mm = fmaxf(mm, pos);
        float sl = 0.0f;
#pragma unroll
        for (int p = 0; p < 8; ++p) sl += __expf(lg[p] - mm);
#pragma unroll
        for (int off = 32; off; off >>= 1) sl += __shfl_xor(sl, off, 64);
        float S = sl * 0.25f + __expf(pos - mm);  // each neg replicated 4x per quad
        float lse = mm + __logf(S);
        contrib = (lse - pos) * hp.scale;
    }
    if (lane == 0) partial[wid] = contrib;
    __syncthreads();
    if (threadIdx.x == 0)
        atomicAdd(out, partial[0] + partial[1] + partial[2] + partial[3]);
}

extern "C" void kernel_launch(void* const* d_in, const int* in_sizes, int n_in,
                              void* d_out, int out_size, void* d_ws, size_t ws_size,
                              hipStream_t stream) {
    const float* z     = (const float*)d_in[0];
    const float* preds = (const float*)d_in[1];
    const int*   nidx  = (const int*)d_in[2];
    float* out = (float*)d_out;

    unsigned* az  = (unsigned*)d_ws;                                 // 4 MB
    unsigned* anf = (unsigned*)((char*)d_ws + (size_t)4194304);      // 2 MB
    unsigned* Wh  = (unsigned*)((char*)d_ws + (size_t)6291456);      // 384 KB
    _Float16* zp  = (_Float16*)((char*)d_ws + (size_t)6684672);      // 12 MB

    const int ks[3] = {1, 5, 21};
    double rw[3] = {1.0, 1.0 / sqrt(5.0), 1.0 / sqrt(21.0)};
    double tot = rw[0] + rw[1] + rw[2];

    HP3 P;
    int maxN = 0;
    for (int i = 0; i < 3; ++i) {
        int L = Tc - ks[i], N = Bc * L;
        P.h[i].L = L; P.h[i].N = N; P.h[i].kh = ks[i];
        P.h[i].scale = (float)(rw[i] / tot / (double)N);
        P.h[i].nxOff = (long long)i * BTc * NNEGc;
        if (N > maxN) maxN = N;
    }

    k_norm<<<BTc / 4, 256, 0, stream>>>(z, preds, az, anf, Wh, out);
    k_gemm<<<dim3(BTc / 64, (3 * Dc) / 64), 256, 0, stream>>>(az, Wh, zp);
    k_loss<<<dim3((maxN + 3) / 4, 3), 256, 0, stream>>>(az, anf, zp, nidx, out, P);
}